// Round 1
// baseline (263.450 us; speedup 1.0000x reference)
//
#include <hip/hip_runtime.h>

// STN forward: B=64, H=W=256, C=3; dense 196608->64->6; affine grid + bilinear.
constexpr int B_   = 64;
constexpr int H_   = 256;
constexpr int W_   = 256;
constexpr int C_   = 3;
constexpr int D_IN = H_ * W_ * C_;   // 196608
constexpr int D_H  = 64;
constexpr int D_OUT = 6;

constexpr int KT       = 64;              // k-tile depth
constexpr int NTILES   = D_IN / KT;       // 3072
constexpr int G1_GRID  = 768;             // split-K blocks
constexpr int TPB_TILES = NTILES / G1_GRID; // 4 tiles per block

// ws layout (floats): [0,4096) h_acc, [4096,4480) mat(64x6)

__global__ void zero_kernel(float* __restrict__ h_acc) {
    int i = blockIdx.x * blockDim.x + threadIdx.x;
    if (i < B_ * D_H) h_acc[i] = 0.0f;
}

// GEMM1: C[64][64] = A(64 x 196608) @ W1(196608 x 64), split-K with atomic epilogue.
// Block: 256 threads, each owns a 4x4 tile of the full 64x64 output.
__global__ __launch_bounds__(256) void gemm1_kernel(
    const float* __restrict__ A, const float* __restrict__ W1,
    float* __restrict__ h_acc)
{
    __shared__ float As[64][KT + 4];  // +4 pad keeps float4 alignment, breaks stride conflicts
    __shared__ float Ws[KT][64];

    const int tid  = threadIdx.x;
    const int r0   = (tid >> 4) << 2;   // 0..60 step 4
    const int c0   = (tid & 15) << 2;   // 0..60 step 4
    const int lrow = tid >> 4;          // loader: 0..15
    const int lf4  = tid & 15;          // loader: 0..15 (float4 index)

    float acc[4][4];
#pragma unroll
    for (int i = 0; i < 4; ++i)
#pragma unroll
        for (int j = 0; j < 4; ++j) acc[i][j] = 0.0f;

    for (int tt = 0; tt < TPB_TILES; ++tt) {
        const int k0 = (blockIdx.x * TPB_TILES + tt) * KT;

        // stage A tile: 64 rows x 64 floats (16 consecutive lanes read 256B contiguous)
#pragma unroll
        for (int it = 0; it < 4; ++it) {
            int row = it * 16 + lrow;
            float4 v = *(const float4*)(A + row * D_IN + k0 + lf4 * 4);
            *(float4*)&As[row][lf4 * 4] = v;
        }
        // stage W1 tile: 64 rows (k) x 64 cols
#pragma unroll
        for (int it = 0; it < 4; ++it) {
            int row = it * 16 + lrow;
            float4 v = *(const float4*)(W1 + (k0 + row) * D_H + lf4 * 4);
            *(float4*)&Ws[row][lf4 * 4] = v;
        }
        __syncthreads();

#pragma unroll
        for (int kk = 0; kk < KT; kk += 4) {
            float4 b0 = *(float4*)&Ws[kk + 0][c0];
            float4 b1 = *(float4*)&Ws[kk + 1][c0];
            float4 b2 = *(float4*)&Ws[kk + 2][c0];
            float4 b3 = *(float4*)&Ws[kk + 3][c0];
#pragma unroll
            for (int i = 0; i < 4; ++i) {
                float4 a = *(float4*)&As[r0 + i][kk];
                acc[i][0] += a.x * b0.x + a.y * b1.x + a.z * b2.x + a.w * b3.x;
                acc[i][1] += a.x * b0.y + a.y * b1.y + a.z * b2.y + a.w * b3.y;
                acc[i][2] += a.x * b0.z + a.y * b1.z + a.z * b2.z + a.w * b3.z;
                acc[i][3] += a.x * b0.w + a.y * b1.w + a.z * b2.w + a.w * b3.w;
            }
        }
        __syncthreads();
    }

#pragma unroll
    for (int i = 0; i < 4; ++i)
#pragma unroll
        for (int j = 0; j < 4; ++j)
            atomicAdd(&h_acc[(r0 + i) * D_H + (c0 + j)], acc[i][j]);
}

// bias+relu on h, then x2 = relu(h @ W2 + b2), mat = theta * x2. One block.
__global__ __launch_bounds__(256) void fc_tail_kernel(
    const float* __restrict__ h_acc, const float* __restrict__ b1,
    const float* __restrict__ W2, const float* __restrict__ b2,
    const float* __restrict__ theta, float* __restrict__ mat)
{
    __shared__ float h[B_][D_H + 1];
    const int t = threadIdx.x;
#pragma unroll
    for (int i = 0; i < (B_ * D_H) / 256; ++i) {
        int idx = i * 256 + t;
        int b = idx >> 6, k = idx & 63;
        h[b][k] = fmaxf(h_acc[idx] + b1[k], 0.0f);
    }
    __syncthreads();
    if (t < B_) {
        float a0 = b2[0], a1 = b2[1], a2 = b2[2], a3 = b2[3], a4 = b2[4], a5 = b2[5];
        for (int k = 0; k < D_H; ++k) {
            float hv = h[t][k];
            a0 += hv * W2[k * 6 + 0];
            a1 += hv * W2[k * 6 + 1];
            a2 += hv * W2[k * 6 + 2];
            a3 += hv * W2[k * 6 + 3];
            a4 += hv * W2[k * 6 + 4];
            a5 += hv * W2[k * 6 + 5];
        }
        mat[t * 6 + 0] = theta[t * 6 + 0] * fmaxf(a0, 0.0f);
        mat[t * 6 + 1] = theta[t * 6 + 1] * fmaxf(a1, 0.0f);
        mat[t * 6 + 2] = theta[t * 6 + 2] * fmaxf(a2, 0.0f);
        mat[t * 6 + 3] = theta[t * 6 + 3] * fmaxf(a3, 0.0f);
        mat[t * 6 + 4] = theta[t * 6 + 4] * fmaxf(a4, 0.0f);
        mat[t * 6 + 5] = theta[t * 6 + 5] * fmaxf(a5, 0.0f);
    }
}

// Affine grid + bilinear sample. One thread per pixel (3 channels).
__global__ __launch_bounds__(256) void sample_kernel(
    const float* __restrict__ img, const float* __restrict__ mat,
    float* __restrict__ out)
{
    const int b   = blockIdx.y;
    const int pix = blockIdx.x * 256 + threadIdx.x;   // 0..65535
    const int iy  = pix >> 8;
    const int ix  = pix & 255;

    const float m00 = mat[b * 6 + 0], m01 = mat[b * 6 + 1], m02 = mat[b * 6 + 2];
    const float m10 = mat[b * 6 + 3], m11 = mat[b * 6 + 4], m12 = mat[b * 6 + 5];

    const float step = 2.0f / 255.0f;
    const float xg = -1.0f + ix * step;
    const float yg = -1.0f + iy * step;
    const float xs = m00 * xg + m01 * yg + m02;
    const float ys = m10 * xg + m11 * yg + m12;

    const float xf = 0.5f * (xs + 1.0f) * 255.0f;
    const float yf = 0.5f * (ys + 1.0f) * 255.0f;

    const int x0 = (int)fminf(fmaxf(floorf(xf), 0.0f), 255.0f);
    const int y0 = (int)fminf(fmaxf(floorf(yf), 0.0f), 255.0f);
    const int x1 = min(x0 + 1, 255);
    const int y1 = min(y0 + 1, 255);

    const float x0f = (float)x0, x1f = (float)x1;
    const float y0f = (float)y0, y1f = (float)y1;
    const float wa = (x1f - xf) * (y1f - yf);
    const float wb = (x1f - xf) * (yf - y0f);
    const float wc = (xf - x0f) * (y1f - yf);
    const float wd = (xf - x0f) * (yf - y0f);

    const float* base = img + b * (H_ * W_ * C_);
    const float* pa = base + (y0 * W_ + x0) * 3;
    const float* pb = base + (y1 * W_ + x0) * 3;
    const float* pc = base + (y0 * W_ + x1) * 3;
    const float* pd = base + (y1 * W_ + x1) * 3;

    float* o = out + ((size_t)b * (H_ * W_) + pix) * 3;
#pragma unroll
    for (int c = 0; c < 3; ++c)
        o[c] = wa * pa[c] + wb * pb[c] + wc * pc[c] + wd * pd[c];
}

extern "C" void kernel_launch(void* const* d_in, const int* in_sizes, int n_in,
                              void* d_out, int out_size, void* d_ws, size_t ws_size,
                              hipStream_t stream) {
    const float* inputs = (const float*)d_in[0];
    const float* W1     = (const float*)d_in[1];
    const float* b1     = (const float*)d_in[2];
    const float* W2     = (const float*)d_in[3];
    const float* b2     = (const float*)d_in[4];
    const float* theta  = (const float*)d_in[5];
    float* out = (float*)d_out;

    float* h_acc = (float*)d_ws;          // 4096 floats
    float* mat   = h_acc + B_ * D_H;      // 384 floats

    zero_kernel<<<16, 256, 0, stream>>>(h_acc);
    gemm1_kernel<<<G1_GRID, 256, 0, stream>>>(inputs, W1, h_acc);
    fc_tail_kernel<<<1, 256, 0, stream>>>(h_acc, b1, W2, b2, theta, mat);
    dim3 sgrid(H_ * W_ / 256, B_);
    sample_kernel<<<sgrid, dim3(256), 0, stream>>>(inputs, mat, out);
}